// Round 2
// 152.584 us; speedup vs baseline: 1.0038x; 1.0038x over previous
//
#include <hip/hip_runtime.h>
#include <climits>

#define EMB 128
#define EMB2 256
#define QBLOCKS 512   // number of qmin-scan blocks (fixed, small)

typedef float v4f __attribute__((ext_vector_type(4)));
typedef int   v4i __attribute__((ext_vector_type(4)));

// ---------------------------------------------------------------------------
// Kernel AB (fused): block 0 computes weff[k] = sum_j Wo[0,128+j]*Wq[j,k];
// blocks 1..QBLOCKS compute per-block qmin partials -> slots[b-1].
// No atomics, no init dependency (every slot written unconditionally).
// ---------------------------------------------------------------------------
__global__ void prep_kernel(const float* __restrict__ Wq,
                            const float* __restrict__ Wo,
                            const int* __restrict__ ei, int E,
                            float* __restrict__ weff,
                            int* __restrict__ slots) {
    if (blockIdx.x == 0) {
        int k = threadIdx.x;  // 256 threads
        float acc = 0.f;
#pragma unroll 8
        for (int j = 0; j < EMB; ++j)
            acc += Wo[EMB + j] * Wq[j * EMB2 + k];
        weff[k] = acc;
        return;
    }
    int m = INT_MAX;
    int nvec = E >> 2;
    int nthreads = QBLOCKS * blockDim.x;
    int tid = (blockIdx.x - 1) * blockDim.x + threadIdx.x;
    const v4i* r0 = (const v4i*)ei;
    const v4i* r1 = (const v4i*)(ei + E);
    for (int v = tid; v < nvec; v += nthreads) {
        v4i a = r0[v];
        v4i b = r1[v];
        int m0 = max(a.x, b.x), m1 = max(a.y, b.y);
        int m2 = max(a.z, b.z), m3 = max(a.w, b.w);
        m = min(m, min(min(m0, m1), min(m2, m3)));
    }
    if (blockIdx.x == 1 && threadIdx.x < (E & 3)) {  // tail edges
        int e = (nvec << 2) + threadIdx.x;
        m = min(m, max(ei[e], ei[e + E]));
    }
#pragma unroll
    for (int off = 32; off; off >>= 1)
        m = min(m, __shfl_xor(m, off, 64));
    __shared__ int sm[4];
    int wid = threadIdx.x >> 6;
    if ((threadIdx.x & 63) == 0) sm[wid] = m;
    __syncthreads();
    if (threadIdx.x == 0)
        slots[blockIdx.x - 1] = min(min(sm[0], sm[1]), min(sm[2], sm[3]));
}

// ---------------------------------------------------------------------------
// Kernel C: per-node dot products -> packed float4 table with qmin shift
// BAKED IN so the edge kernel needs only TWO gathers per edge:
//   A = Wo[0,0:128].z[i]
//   B = weff[0:128].z[i]
//   C'= weff[128:256].z0[i - qmin]   (0 if i < qmin; those entries unused)
//   Q[i] = { A, B, A+C', B+C' }
// Edge identity: qid = max(a,b)-qmin, so the C' term lives at node max(a,b):
//   a>=b: out = Q[a].z + Q[b].y + bo   (covers a==b)
//   a< b: out = Q[a].x + Q[b].w + bo
// Preamble reduces L2-resident slots[512] -> qmin per block (cheap).
// ---------------------------------------------------------------------------
__global__ void node_dots_kernel(const float* __restrict__ z,
                                 const float* __restrict__ z0,
                                 const float* __restrict__ Wo,
                                 const float* __restrict__ weff,
                                 const int* __restrict__ slots,
                                 v4f* __restrict__ tab,
                                 int N) {
    __shared__ int sq[5];
    {
        int t = threadIdx.x;  // 256 threads
        int mm = min(slots[t], slots[t + 256]);
#pragma unroll
        for (int off = 32; off; off >>= 1)
            mm = min(mm, __shfl_xor(mm, off, 64));
        if ((t & 63) == 0) sq[t >> 6] = mm;
        __syncthreads();
        if (t == 0) sq[4] = min(min(sq[0], sq[1]), min(sq[2], sq[3]));
        __syncthreads();
    }
    const int qmin = sq[4];

    int gtid = blockIdx.x * blockDim.x + threadIdx.x;
    int wave = gtid >> 6;
    int lane = gtid & 63;
    int sub = lane >> 5;   // which row of the pair
    int c = lane & 31;     // column group (4 floats)
    int row = wave * 2 + sub;
    if (row >= N) return;

    v4f w1 = ((const v4f*)Wo)[c];          // Wo[0, 4c:4c+4]
    v4f wa = ((const v4f*)weff)[c];        // weff[0:128]
    v4f wb = ((const v4f*)weff)[32 + c];   // weff[128:256]

    v4f zv  = __builtin_nontemporal_load(((const v4f*)(z  + (size_t)row * EMB)) + c);

    float p1 = w1.x * zv.x + w1.y * zv.y + w1.z * zv.z + w1.w * zv.w;
    float p2 = wa.x * zv.x + wa.y * zv.y + wa.z * zv.z + wa.w * zv.w;
    float p3 = 0.f;
    int zr = row - qmin;
    if (zr >= 0) {  // wave-uniform except at one boundary wave
        v4f z0v = __builtin_nontemporal_load(((const v4f*)(z0 + (size_t)zr * EMB)) + c);
        p3 = wb.x * z0v.x + wb.y * z0v.y + wb.z * z0v.z + wb.w * z0v.w;
    }

#pragma unroll
    for (int off = 16; off; off >>= 1) {
        p1 += __shfl_xor(p1, off, 64);
        p2 += __shfl_xor(p2, off, 64);
        p3 += __shfl_xor(p3, off, 64);
    }
    if (c == 0) {
        v4f r; r.x = p1; r.y = p2; r.z = p1 + p3; r.w = p2 + p3;
        tab[row] = r;
    }
}

// ---------------------------------------------------------------------------
// Kernel D: per-edge combine, 4 edges/thread via int4, TWO 4B gathers/edge.
//   a>=b: out = qt[4a+2] + qt[4b+1] + bo
//   a< b: out = qt[4a+0] + qt[4b+3] + bo
// No qmin needed (shift baked into table), no preamble, no syncthreads.
// ---------------------------------------------------------------------------
__global__ void edge_out_kernel(const int* __restrict__ ei,
                                const float* __restrict__ qt,
                                const float* __restrict__ bo,
                                float* __restrict__ out, int E) {
    const float b0 = *bo;
    int t = blockIdx.x * blockDim.x + threadIdx.x;
    int e4 = t << 2;
    if (e4 + 3 < E) {
        v4i a = *(const v4i*)(ei + e4);
        v4i b = *(const v4i*)(ei + E + e4);
        v4f r;
        {
            int g = (a.x >= b.x);
            r.x = qt[(a.x << 2) | (g ? 2 : 0)] + qt[(b.x << 2) | (g ? 1 : 3)] + b0;
        }
        {
            int g = (a.y >= b.y);
            r.y = qt[(a.y << 2) | (g ? 2 : 0)] + qt[(b.y << 2) | (g ? 1 : 3)] + b0;
        }
        {
            int g = (a.z >= b.z);
            r.z = qt[(a.z << 2) | (g ? 2 : 0)] + qt[(b.z << 2) | (g ? 1 : 3)] + b0;
        }
        {
            int g = (a.w >= b.w);
            r.w = qt[(a.w << 2) | (g ? 2 : 0)] + qt[(b.w << 2) | (g ? 1 : 3)] + b0;
        }
        __builtin_nontemporal_store(r, (v4f*)(out + e4));
    } else {
        for (int e = e4; e < E; ++e) {
            int a = ei[e], b = ei[e + E];
            int g = (a >= b);
            out[e] = qt[(a << 2) | (g ? 2 : 0)] + qt[(b << 2) | (g ? 1 : 3)] + b0;
        }
    }
}

extern "C" void kernel_launch(void* const* d_in, const int* in_sizes, int n_in,
                              void* d_out, int out_size, void* d_ws, size_t ws_size,
                              hipStream_t stream) {
    const float* z    = (const float*)d_in[0];
    const int*   ei   = (const int*)d_in[1];
    const float* z0   = (const float*)d_in[2];
    const float* Wq   = (const float*)d_in[3];
    const float* Wo   = (const float*)d_in[4];
    const float* bo   = (const float*)d_in[5];
    float* out = (float*)d_out;

    int N = in_sizes[0] / EMB;   // 100000
    int E = in_sizes[1] / 2;     // 1000000

    // Workspace layout: tab[N] (float4, 16B-aligned) | weff[256] | slots[512]
    v4f* tab = (v4f*)d_ws;
    float* weff = (float*)(tab + N);
    int* slots = (int*)(weff + EMB2);

    // AB: weff (block 0) + qmin partials -> slots (blocks 1..512)
    prep_kernel<<<1 + QBLOCKS, 256, 0, stream>>>(Wq, Wo, ei, E, weff, slots);

    // C: per-node dots (qmin-shifted C' term), one wave per row pair
    int pairs = (N + 1) / 2;
    int blocksC = (pairs + 3) / 4;
    node_dots_kernel<<<blocksC, 256, 0, stream>>>(z, z0, Wo, weff, slots, tab, N);

    // D: per-edge combine, 4 edges/thread, 2 gathers/edge
    int threadsD = (E + 3) / 4;
    int blocksD = (threadsD + 255) / 256;
    edge_out_kernel<<<blocksD, 256, 0, stream>>>(ei, (const float*)tab, bo, out, E);
}